// Round 7
// baseline (323.391 us; speedup 1.0000x reference)
//
#include <hip/hip_runtime.h>
#include <hip/hip_bf16.h>
#include <math.h>

#define TSEQ 2048
#define NB 2
#define DM 1024
#define NH 16
#define DHD 64

typedef __attribute__((ext_vector_type(8))) __bf16 bf16x8;
typedef __attribute__((ext_vector_type(8))) short s16x8;
typedef __attribute__((ext_vector_type(4))) float f32x4;

__device__ __forceinline__ bf16x8 ld_bf16x8(const void* p) {
  s16x8 v = *reinterpret_cast<const s16x8*>(p);
  return __builtin_bit_cast(bf16x8, v);
}

#define GLL16(g, l) __builtin_amdgcn_global_load_lds( \
    (const __attribute__((address_space(1))) void*)(g), \
    (__attribute__((address_space(3))) void*)(l), 16, 0, 0)

// ---------- transpose + cast fp32 -> bf16 : out[C][R] = in[R][C] ----------
__global__ __launch_bounds__(256) void k_transpose_cast(
    const float* __restrict__ in, __hip_bfloat16* __restrict__ out,
    int R, int C) {
  __shared__ float t[32][33];
  const int tx = threadIdx.x, ty = threadIdx.y;
  const int c0 = blockIdx.x * 32, r0 = blockIdx.y * 32;
#pragma unroll
  for (int j = 0; j < 4; ++j)
    t[ty + j * 8][tx] = in[(size_t)(r0 + ty + j * 8) * C + c0 + tx];
  __syncthreads();
#pragma unroll
  for (int j = 0; j < 4; ++j) {
    const int oc = ty + j * 8;
    out[(size_t)(c0 + oc) * R + r0 + tx] = __float2bfloat16(t[tx][oc]);
  }
}

// ---------- elementwise cast fp32 -> bf16 (exact-multiple sizes) ----------
__global__ __launch_bounds__(256) void k_cast_bf16(
    const float* __restrict__ in, __hip_bfloat16* __restrict__ out) {
  const int i = (blockIdx.x * 256 + threadIdx.x) * 4;
  const float4 v = *reinterpret_cast<const float4*>(in + i);
  struct B4 { __hip_bfloat16 a, b, c, d; } o;
  o.a = __float2bfloat16(v.x); o.b = __float2bfloat16(v.y);
  o.c = __float2bfloat16(v.z); o.d = __float2bfloat16(v.w);
  *reinterpret_cast<B4*>(out + i) = o;
}

// ---------- LayerNorm rows of [4096][1024], fp32 in -> bf16 out ----------
__global__ __launch_bounds__(256) void k_layernorm(
    const float* __restrict__ x, const float* __restrict__ g,
    const float* __restrict__ b, __hip_bfloat16* __restrict__ out) {
  const int row = blockIdx.x, tid = threadIdx.x;
  const float4 v = reinterpret_cast<const float4*>(x + (size_t)row * DM)[tid];
  float s = v.x + v.y + v.z + v.w;
  __shared__ float r1[4], r2[4];
#pragma unroll
  for (int off = 32; off; off >>= 1) s += __shfl_xor(s, off);
  if ((tid & 63) == 0) r1[tid >> 6] = s;
  __syncthreads();
  const float mu = (r1[0] + r1[1] + r1[2] + r1[3]) * (1.f / DM);
  const float dx = v.x - mu, dy = v.y - mu, dz = v.z - mu, dw = v.w - mu;
  float q = dx * dx + dy * dy + dz * dz + dw * dw;
#pragma unroll
  for (int off = 32; off; off >>= 1) q += __shfl_xor(q, off);
  if ((tid & 63) == 0) r2[tid >> 6] = q;
  __syncthreads();
  const float rs = rsqrtf((r2[0] + r2[1] + r2[2] + r2[3]) * (1.f / DM) + 1e-5f);
  const float4 gv = reinterpret_cast<const float4*>(g)[tid];
  const float4 bv = reinterpret_cast<const float4*>(b)[tid];
  struct B4 { __hip_bfloat16 a, b, c, d; } o;
  o.a = __float2bfloat16(dx * rs * gv.x + bv.x);
  o.b = __float2bfloat16(dy * rs * gv.y + bv.y);
  o.c = __float2bfloat16(dz * rs * gv.z + bv.z);
  o.d = __float2bfloat16(dw * rs * gv.w + bv.w);
  reinterpret_cast<B4*>(out + (size_t)row * DM)[tid] = o;
}

// ---------- generic 128x128 bf16 MFMA GEMM, C = A[M][K] * BT[N][K]^T ----------
// MODE 0: QKV epilogue  MODE 1: R epilogue  MODE 2: fp32 out epilogue
template <int MODE>
__global__ __launch_bounds__(256) void k_gemm_bt(
    const __hip_bfloat16* __restrict__ A, const __hip_bfloat16* __restrict__ BT,
    int M, int N, int K, float* __restrict__ outF,
    __hip_bfloat16* __restrict__ o_qw, __hip_bfloat16* __restrict__ o_qr,
    __hip_bfloat16* __restrict__ o_k, __hip_bfloat16* __restrict__ o_vT,
    const float* __restrict__ rwb, const float* __restrict__ rrb,
    __hip_bfloat16* __restrict__ o_rT) {
  __shared__ __align__(16) __hip_bfloat16 As[128 * 32];
  __shared__ __align__(16) __hip_bfloat16 Bs[128 * 32];
  const int tid = threadIdx.x, lane = tid & 63;
  const int ntn = N >> 7;
  const int m0 = (blockIdx.x / ntn) * 128, n0 = (blockIdx.x % ntn) * 128;
  const int wid = tid >> 6;
  const int wr = (wid >> 1) * 64, wc = (wid & 1) * 64;
  const int fr = lane & 15, fq = lane >> 4;
  const int srow = tid >> 2, scol = (tid & 3) * 8;
  const __hip_bfloat16* aSrc = A + (size_t)(m0 + srow) * K + scol;
  const __hip_bfloat16* bSrc = BT + (size_t)(n0 + srow) * K + scol;
  char* aDst = (char*)As + (tid - lane) * 16;
  char* bDst = (char*)Bs + (tid - lane) * 16;
  f32x4 acc[4][4] = {};
  for (int k0 = 0; k0 < K; k0 += 32) {
    GLL16(aSrc + k0, aDst);
    GLL16(aSrc + (size_t)64 * K + k0, aDst + 4096);
    GLL16(bSrc + k0, bDst);
    GLL16(bSrc + (size_t)64 * K + k0, bDst + 4096);
    __syncthreads();
    bf16x8 af[4], bfr[4];
#pragma unroll
    for (int mi = 0; mi < 4; ++mi)
      af[mi] = ld_bf16x8(As + (wr + mi * 16 + fr) * 32 + fq * 8);
#pragma unroll
    for (int ni = 0; ni < 4; ++ni)
      bfr[ni] = ld_bf16x8(Bs + (wc + ni * 16 + fr) * 32 + fq * 8);
#pragma unroll
    for (int mi = 0; mi < 4; ++mi)
#pragma unroll
      for (int ni = 0; ni < 4; ++ni)
        acc[mi][ni] = __builtin_amdgcn_mfma_f32_16x16x32_bf16(
            af[mi], bfr[ni], acc[mi][ni], 0, 0, 0);
    __syncthreads();
  }
#pragma unroll
  for (int mi = 0; mi < 4; ++mi) {
#pragma unroll
    for (int ni = 0; ni < 4; ++ni) {
#pragma unroll
      for (int j = 0; j < 4; ++j) {
        const int r = m0 + wr + mi * 16 + fq * 4 + j;
        const int c = n0 + wc + ni * 16 + fr;
        const float v = acc[mi][ni][j];
        if (MODE == 2) {
          outF[(size_t)r * N + c] = v;
        } else if (MODE == 1) {
          const int h = c >> 6, d = c & 63;
          o_rT[((size_t)h * TSEQ + r) * DHD + d] = __float2bfloat16(v);
        } else {
          const int t = r >> 1, bb = r & 1;
          if (c < 1024) {
            const int h = c >> 6, d = c & 63;
            const size_t o = (((size_t)(bb * NH + h)) * TSEQ + t) * DHD + d;
            o_qw[o] = __float2bfloat16(v + rwb[c]);
            o_qr[o] = __float2bfloat16(v + rrb[c]);
          } else if (c < 2048) {
            const int e = c - 1024, h = e >> 6, d = e & 63;
            o_k[(((size_t)(bb * NH + h)) * TSEQ + t) * DHD + d] = __float2bfloat16(v);
          } else {
            const int e = c - 2048, h = e >> 6, d = e & 63;
            o_vT[(((size_t)(bb * NH + h)) * DHD + d) * TSEQ + t] = __float2bfloat16(v);
          }
        }
      }
    }
  }
}

// ---------- fused causal rel-attention, swapped core, balanced k-split ----------
// Block = (head, pair p & 127-p); wave w = k-half h of both tiles.
// Every wave does 16-17 iterations -> all 2048 blocks identical duration,
// 8 blocks/CU co-resident = 4 waves/SIMD CONSTANT occupancy.
// Swapped math identical to R5/R6 (proven): S^T=mfma(K,Q), band mfma(R,Qr)
// b128-written braw[fr][16pp+4fq], consumed braw[fr][15-fr+koff];
// PV swapped O^T[d][q=fr]; m,l per-lane scalars -> lane-aligned merge.
// End merge: wave1 stores (O,m,l) into LDS overlay on braw; wave0 merges.
__global__ __launch_bounds__(128, 4) void k_attn(
    const __hip_bfloat16* __restrict__ qw, const __hip_bfloat16* __restrict__ qr,
    const __hip_bfloat16* __restrict__ kb, const __hip_bfloat16* __restrict__ vT,
    const __hip_bfloat16* __restrict__ rT, __hip_bfloat16* __restrict__ av) {
  const int tid = threadIdx.x, lane = tid & 63;
  const int w = __builtin_amdgcn_readfirstlane(tid >> 6);  // wave id 0/1 (SGPR)
  const int fr = lane & 15, fq = lane >> 4;
  const int bid = blockIdx.x;
  const int xcd = bid & 7, idx = bid >> 3;     // idx 0..255
  const int bh = xcd * 4 + (idx & 3);          // 4 heads per XCD (L2-local)
  const int pair = idx >> 2;                   // 0..63
  const int bb = bh >> 4, h = bh & 15;
  const size_t bhs = (size_t)bh;
  const __hip_bfloat16* Kp = kb + bhs * TSEQ * DHD;
  const __hip_bfloat16* Vt = vT + bhs * DHD * TSEQ;
  const __hip_bfloat16* Rp = rT + (size_t)h * TSEQ * DHD;
  __shared__ __align__(16) float braw[2][16][88];
  __shared__ __align__(16) __hip_bfloat16 plq[2][16][72];
  const f32x4 zero = {0.f, 0.f, 0.f, 0.f};

  f32x4 oo[2][4] = {};
  float mm[2] = {-INFINITY, -INFINITY}, ll[2] = {0.f, 0.f};

#pragma unroll
  for (int t = 0; t < 2; ++t) {
    const int p = (t == 0) ? pair : 127 - pair;
    const int iw0 = p * 16;
    const int nk = (p >> 2) + 1;
    const int kh = (nk + 1) >> 1;
    const int kbeg = w ? kh : 0, kend = w ? nk : kh;
    const __hip_bfloat16* qwp = qw + (bhs * TSEQ + iw0 + fr) * DHD + fq * 8;
    const __hip_bfloat16* qrp = qr + (bhs * TSEQ + iw0 + fr) * DHD + fq * 8;
    const bf16x8 qwf0 = ld_bf16x8(qwp), qwf1 = ld_bf16x8(qwp + 32);
    const bf16x8 qrf0 = ld_bf16x8(qrp), qrf1 = ld_bf16x8(qrp + 32);
    f32x4 o[4] = {};
    float mrow = -INFINITY, lrow = 0.f;
    // running bases (incremented per iteration; no per-iter 64-bit recompute)
    const __hip_bfloat16* kBase = Kp + (size_t)(kbeg * 64 + fr) * DHD + fq * 8;
    const __hip_bfloat16* vBase = Vt + (size_t)fr * TSEQ + kbeg * 64 + fq * 8;
    int rIdx = TSEQ - 16 - iw0 + kbeg * 64;
    int thr = iw0 + fr - kbeg * 64;
    for (int kt = kbeg; kt < kend; ++kt) {
      // ---- V prefetch (consumed at iteration end) ----
      bf16x8 vv[8];
#pragma unroll
      for (int c = 0; c < 2; ++c)
#pragma unroll
        for (int nd = 0; nd < 4; ++nd)
          vv[c * 4 + nd] = ld_bf16x8(vBase + (size_t)(16 * nd) * TSEQ + 32 * c);
      // ---- S^T = mfma(K, Q): st[n][j] = S[q=fr][koff=16n+4fq+j] ----
      f32x4 st[4];
#pragma unroll
      for (int n = 0; n < 4; ++n) {
        st[n] = __builtin_amdgcn_mfma_f32_16x16x32_bf16(ld_bf16x8(kBase + n * 1024), qwf0, zero, 0, 0, 0);
        st[n] = __builtin_amdgcn_mfma_f32_16x16x32_bf16(ld_bf16x8(kBase + n * 1024 + 32), qwf1, st[n], 0, 0, 0);
      }
      // ---- band swapped: D[m=16pp+4fq+jj][q=fr] -> b128 write ----
#pragma unroll
      for (int pp = 0; pp < 5; ++pp) {
        int ridx = rIdx + pp * 16 + fr;
        ridx = ridx < 0 ? 0 : (ridx > TSEQ - 1 ? TSEQ - 1 : ridx);  // masked region only
        const __hip_bfloat16* rp = Rp + (size_t)ridx * DHD + fq * 8;
        f32x4 br = __builtin_amdgcn_mfma_f32_16x16x32_bf16(ld_bf16x8(rp), qrf0, zero, 0, 0, 0);
        br = __builtin_amdgcn_mfma_f32_16x16x32_bf16(ld_bf16x8(rp + 32), qrf1, br, 0, 0, 0);
        *reinterpret_cast<f32x4*>(&braw[w][fr][pp * 16 + 4 * fq]) = br;
      }
      // ---- scores + in-register online softmax (q = fr) ----
      const float* brd = &braw[w][fr][15 - fr];
      float mx = -INFINITY;
#pragma unroll
      for (int n = 0; n < 4; ++n) {
#pragma unroll
        for (int j = 0; j < 4; ++j) {
          const int koff = 16 * n + 4 * fq + j;
          const float s = (koff > thr) ? -INFINITY : (st[n][j] + brd[koff]) * 0.125f;
          st[n][j] = s;
          mx = fmaxf(mx, s);
        }
      }
      mx = fmaxf(mx, __shfl_xor(mx, 16));
      mx = fmaxf(mx, __shfl_xor(mx, 32));
      const float mn = fmaxf(mrow, mx);
      const float al = __expf(mrow - mn);
      mrow = mn;
      float rs = 0.f;
#pragma unroll
      for (int n = 0; n < 4; ++n)
#pragma unroll
        for (int j = 0; j < 4; ++j) {
          const float pv = __expf(st[n][j] - mn);
          st[n][j] = pv;
          rs += pv;
        }
      rs += __shfl_xor(rs, 16);
      rs += __shfl_xor(rs, 32);
      lrow = lrow * al + rs;
#pragma unroll
      for (int nd = 0; nd < 4; ++nd) o[nd] *= al;
      // ---- P store: packed b64 at P[q=fr][16n+4fq] ----
      struct B4 { __hip_bfloat16 a, b, c, d; };
#pragma unroll
      for (int n = 0; n < 4; ++n) {
        B4 pk;
        pk.a = __float2bfloat16(st[n][0]);
        pk.b = __float2bfloat16(st[n][1]);
        pk.c = __float2bfloat16(st[n][2]);
        pk.d = __float2bfloat16(st[n][3]);
        *reinterpret_cast<B4*>(&plq[w][fr][16 * n + 4 * fq]) = pk;
      }
      // ---- O^T += V^T . P^T ----
#pragma unroll
      for (int c = 0; c < 2; ++c) {
        const bf16x8 pf = ld_bf16x8(&plq[w][fr][8 * fq + 32 * c]);
#pragma unroll
        for (int nd = 0; nd < 4; ++nd)
          o[nd] = __builtin_amdgcn_mfma_f32_16x16x32_bf16(vv[c * 4 + nd], pf, o[nd], 0, 0, 0);
      }
      kBase += 64 * DHD;
      vBase += 64;
      rIdx += 64;
      thr -= 64;
    }
#pragma unroll
    for (int nd = 0; nd < 4; ++nd) oo[t][nd] = o[nd];
    mm[t] = mrow; ll[t] = lrow;
  }

  // ---- lane-aligned merge of the two k-halves (overlay on braw) ----
  float* ob = (float*)&braw[0][0][0];   // 2048 floats: [2 tiles][64 lanes][16]
  float* mlb = ob + 2048;               // 256 floats:  [2 tiles][64 lanes][2]
  __syncthreads();                      // loops done before overlay writes
  if (w == 1) {
#pragma unroll
    for (int t = 0; t < 2; ++t) {
#pragma unroll
      for (int nd = 0; nd < 4; ++nd)
        *reinterpret_cast<f32x4*>(&ob[(t * 64 + lane) * 16 + nd * 4]) = oo[t][nd];
      mlb[(t * 64 + lane) * 2 + 0] = mm[t];
      mlb[(t * 64 + lane) * 2 + 1] = ll[t];
    }
  }
  __syncthreads();
  if (w == 0) {
    struct B4 { __hip_bfloat16 a, b, c, d; };
#pragma unroll
    for (int t = 0; t < 2; ++t) {
      const int p = (t == 0) ? pair : 127 - pair;
      const int i = p * 16 + fr;
      const float m1 = mlb[(t * 64 + lane) * 2 + 0];
      const float l1 = mlb[(t * 64 + lane) * 2 + 1];
      const float mn = fmaxf(mm[t], m1);
      const float a0 = __expf(mm[t] - mn);
      const float a1 = __expf(m1 - mn);
      const float linv = 1.f / (ll[t] * a0 + l1 * a1);
#pragma unroll
      for (int nd = 0; nd < 4; ++nd) {
        const f32x4 o1 = *reinterpret_cast<const f32x4*>(&ob[(t * 64 + lane) * 16 + nd * 4]);
        B4 pack;
        pack.a = __float2bfloat16((oo[t][nd][0] * a0 + o1[0] * a1) * linv);
        pack.b = __float2bfloat16((oo[t][nd][1] * a0 + o1[1] * a1) * linv);
        pack.c = __float2bfloat16((oo[t][nd][2] * a0 + o1[2] * a1) * linv);
        pack.d = __float2bfloat16((oo[t][nd][3] * a0 + o1[3] * a1) * linv);
        *reinterpret_cast<B4*>(av + ((size_t)i * NB + bb) * DM + h * DHD + 16 * nd + 4 * fq) = pack;
      }
    }
  }
}

extern "C" void kernel_launch(void* const* d_in, const int* in_sizes, int n_in,
                              void* d_out, int out_size, void* d_ws, size_t ws_size,
                              hipStream_t stream) {
  (void)in_sizes; (void)n_in; (void)out_size; (void)ws_size;
  const float* x    = (const float*)d_in[0];
  const float* pos  = (const float*)d_in[1];
  const float* ln_g = (const float*)d_in[2];
  const float* ln_b = (const float*)d_in[3];
  const float* Wqkv = (const float*)d_in[4];
  const float* Wr   = (const float*)d_in[5];
  const float* Wo   = (const float*)d_in[6];
  const float* rwb  = (const float*)d_in[7];
  const float* rrb  = (const float*)d_in[8];
  float* out = (float*)d_out;

  char* ws = (char*)d_ws;
  size_t off = 0;
  auto alloc = [&](size_t n) {
    char* p = ws + off; off += (n + 255) & ~(size_t)255; return p;
  };
  __hip_bfloat16* wqkvT = (__hip_bfloat16*)alloc((size_t)3072 * 1024 * 2);
  __hip_bfloat16* wrT   = (__hip_bfloat16*)alloc((size_t)1024 * 1024 * 2);
  __hip_bfloat16* woT   = (__hip_bfloat16*)alloc((size_t)1024 * 1024 * 2);
  __hip_bfloat16* posb  = (__hip_bfloat16*)alloc((size_t)2048 * 1024 * 2);
  __hip_bfloat16* xn    = (__hip_bfloat16*)alloc((size_t)4096 * 1024 * 2);
  __hip_bfloat16* qwb   = (__hip_bfloat16*)alloc((size_t)NB * NH * TSEQ * DHD * 2);
  __hip_bfloat16* qrb   = (__hip_bfloat16*)alloc((size_t)NB * NH * TSEQ * DHD * 2);
  __hip_bfloat16* kbb   = (__hip_bfloat16*)alloc((size_t)NB * NH * TSEQ * DHD * 2);
  __hip_bfloat16* vTb   = (__hip_bfloat16*)alloc((size_t)NB * NH * TSEQ * DHD * 2);
  __hip_bfloat16* rTb   = (__hip_bfloat16*)alloc((size_t)NH * TSEQ * DHD * 2);
  __hip_bfloat16* avb   = (__hip_bfloat16*)alloc((size_t)4096 * 1024 * 2);

  const dim3 tb(32, 8);
  k_transpose_cast<<<dim3(3072 / 32, 1024 / 32), tb, 0, stream>>>(Wqkv, wqkvT, 1024, 3072);
  k_transpose_cast<<<dim3(1024 / 32, 1024 / 32), tb, 0, stream>>>(Wr, wrT, 1024, 1024);
  k_transpose_cast<<<dim3(1024 / 32, 1024 / 32), tb, 0, stream>>>(Wo, woT, 1024, 1024);
  k_cast_bf16<<<(2048 * 1024) / 1024, 256, 0, stream>>>(pos, posb);
  k_layernorm<<<4096, 256, 0, stream>>>(x, ln_g, ln_b, xn);
  k_gemm_bt<0><<<32 * 24, 256, 0, stream>>>(xn, wqkvT, 4096, 3072, 1024,
      nullptr, qwb, qrb, kbb, vTb, rwb, rrb, nullptr);
  k_gemm_bt<1><<<16 * 8, 256, 0, stream>>>(posb, wrT, 2048, 1024, 1024,
      nullptr, nullptr, nullptr, nullptr, nullptr, nullptr, nullptr, rTb);
  k_attn<<<2048, 128, 0, stream>>>(qwb, qrb, kbb, vTb, rTb, avb);
  k_gemm_bt<2><<<32 * 8, 256, 0, stream>>>(avb, woT, 4096, 1024, 1024,
      out, nullptr, nullptr, nullptr, nullptr, nullptr, nullptr, nullptr);
}

// Round 8
// 212.079 us; speedup vs baseline: 1.5249x; 1.5249x over previous
//
#include <hip/hip_runtime.h>
#include <hip/hip_bf16.h>
#include <math.h>

#define TSEQ 2048
#define NB 2
#define DM 1024
#define NH 16
#define DHD 64

typedef __attribute__((ext_vector_type(8))) __bf16 bf16x8;
typedef __attribute__((ext_vector_type(8))) short s16x8;
typedef __attribute__((ext_vector_type(4))) float f32x4;

__device__ __forceinline__ bf16x8 ld_bf16x8(const void* p) {
  s16x8 v = *reinterpret_cast<const s16x8*>(p);
  return __builtin_bit_cast(bf16x8, v);
}

#define GLL16(g, l) __builtin_amdgcn_global_load_lds( \
    (const __attribute__((address_space(1))) void*)(g), \
    (__attribute__((address_space(3))) void*)(l), 16, 0, 0)

// ---------- transpose + cast fp32 -> bf16 : out[C][R] = in[R][C] ----------
__global__ __launch_bounds__(256) void k_transpose_cast(
    const float* __restrict__ in, __hip_bfloat16* __restrict__ out,
    int R, int C) {
  __shared__ float t[32][33];
  const int tx = threadIdx.x, ty = threadIdx.y;
  const int c0 = blockIdx.x * 32, r0 = blockIdx.y * 32;
#pragma unroll
  for (int j = 0; j < 4; ++j)
    t[ty + j * 8][tx] = in[(size_t)(r0 + ty + j * 8) * C + c0 + tx];
  __syncthreads();
#pragma unroll
  for (int j = 0; j < 4; ++j) {
    const int oc = ty + j * 8;
    out[(size_t)(c0 + oc) * R + r0 + tx] = __float2bfloat16(t[tx][oc]);
  }
}

// ---------- elementwise cast fp32 -> bf16 (exact-multiple sizes) ----------
__global__ __launch_bounds__(256) void k_cast_bf16(
    const float* __restrict__ in, __hip_bfloat16* __restrict__ out) {
  const int i = (blockIdx.x * 256 + threadIdx.x) * 4;
  const float4 v = *reinterpret_cast<const float4*>(in + i);
  struct B4 { __hip_bfloat16 a, b, c, d; } o;
  o.a = __float2bfloat16(v.x); o.b = __float2bfloat16(v.y);
  o.c = __float2bfloat16(v.z); o.d = __float2bfloat16(v.w);
  *reinterpret_cast<B4*>(out + i) = o;
}

// ---------- LayerNorm rows of [4096][1024], fp32 in -> bf16 out ----------
__global__ __launch_bounds__(256) void k_layernorm(
    const float* __restrict__ x, const float* __restrict__ g,
    const float* __restrict__ b, __hip_bfloat16* __restrict__ out) {
  const int row = blockIdx.x, tid = threadIdx.x;
  const float4 v = reinterpret_cast<const float4*>(x + (size_t)row * DM)[tid];
  float s = v.x + v.y + v.z + v.w;
  __shared__ float r1[4], r2[4];
#pragma unroll
  for (int off = 32; off; off >>= 1) s += __shfl_xor(s, off);
  if ((tid & 63) == 0) r1[tid >> 6] = s;
  __syncthreads();
  const float mu = (r1[0] + r1[1] + r1[2] + r1[3]) * (1.f / DM);
  const float dx = v.x - mu, dy = v.y - mu, dz = v.z - mu, dw = v.w - mu;
  float q = dx * dx + dy * dy + dz * dz + dw * dw;
#pragma unroll
  for (int off = 32; off; off >>= 1) q += __shfl_xor(q, off);
  if ((tid & 63) == 0) r2[tid >> 6] = q;
  __syncthreads();
  const float rs = rsqrtf((r2[0] + r2[1] + r2[2] + r2[3]) * (1.f / DM) + 1e-5f);
  const float4 gv = reinterpret_cast<const float4*>(g)[tid];
  const float4 bv = reinterpret_cast<const float4*>(b)[tid];
  struct B4 { __hip_bfloat16 a, b, c, d; } o;
  o.a = __float2bfloat16(dx * rs * gv.x + bv.x);
  o.b = __float2bfloat16(dy * rs * gv.y + bv.y);
  o.c = __float2bfloat16(dz * rs * gv.z + bv.z);
  o.d = __float2bfloat16(dw * rs * gv.w + bv.w);
  reinterpret_cast<B4*>(out + (size_t)row * DM)[tid] = o;
}

// ---------- generic 128x128 bf16 MFMA GEMM, C = A[M][K] * BT[N][K]^T ----------
// MODE 0: QKV epilogue  MODE 1: R epilogue  MODE 2: fp32 out epilogue
template <int MODE>
__global__ __launch_bounds__(256) void k_gemm_bt(
    const __hip_bfloat16* __restrict__ A, const __hip_bfloat16* __restrict__ BT,
    int M, int N, int K, float* __restrict__ outF,
    __hip_bfloat16* __restrict__ o_qw, __hip_bfloat16* __restrict__ o_qr,
    __hip_bfloat16* __restrict__ o_k, __hip_bfloat16* __restrict__ o_vT,
    const float* __restrict__ rwb, const float* __restrict__ rrb,
    __hip_bfloat16* __restrict__ o_rT) {
  __shared__ __align__(16) __hip_bfloat16 As[128 * 32];
  __shared__ __align__(16) __hip_bfloat16 Bs[128 * 32];
  const int tid = threadIdx.x, lane = tid & 63;
  const int ntn = N >> 7;
  const int m0 = (blockIdx.x / ntn) * 128, n0 = (blockIdx.x % ntn) * 128;
  const int wid = tid >> 6;
  const int wr = (wid >> 1) * 64, wc = (wid & 1) * 64;
  const int fr = lane & 15, fq = lane >> 4;
  const int srow = tid >> 2, scol = (tid & 3) * 8;
  const __hip_bfloat16* aSrc = A + (size_t)(m0 + srow) * K + scol;
  const __hip_bfloat16* bSrc = BT + (size_t)(n0 + srow) * K + scol;
  char* aDst = (char*)As + (tid - lane) * 16;
  char* bDst = (char*)Bs + (tid - lane) * 16;
  f32x4 acc[4][4] = {};
  for (int k0 = 0; k0 < K; k0 += 32) {
    GLL16(aSrc + k0, aDst);
    GLL16(aSrc + (size_t)64 * K + k0, aDst + 4096);
    GLL16(bSrc + k0, bDst);
    GLL16(bSrc + (size_t)64 * K + k0, bDst + 4096);
    __syncthreads();
    bf16x8 af[4], bfr[4];
#pragma unroll
    for (int mi = 0; mi < 4; ++mi)
      af[mi] = ld_bf16x8(As + (wr + mi * 16 + fr) * 32 + fq * 8);
#pragma unroll
    for (int ni = 0; ni < 4; ++ni)
      bfr[ni] = ld_bf16x8(Bs + (wc + ni * 16 + fr) * 32 + fq * 8);
#pragma unroll
    for (int mi = 0; mi < 4; ++mi)
#pragma unroll
      for (int ni = 0; ni < 4; ++ni)
        acc[mi][ni] = __builtin_amdgcn_mfma_f32_16x16x32_bf16(
            af[mi], bfr[ni], acc[mi][ni], 0, 0, 0);
    __syncthreads();
  }
#pragma unroll
  for (int mi = 0; mi < 4; ++mi) {
#pragma unroll
    for (int ni = 0; ni < 4; ++ni) {
#pragma unroll
      for (int j = 0; j < 4; ++j) {
        const int r = m0 + wr + mi * 16 + fq * 4 + j;
        const int c = n0 + wc + ni * 16 + fr;
        const float v = acc[mi][ni][j];
        if (MODE == 2) {
          outF[(size_t)r * N + c] = v;
        } else if (MODE == 1) {
          const int h = c >> 6, d = c & 63;
          o_rT[((size_t)h * TSEQ + r) * DHD + d] = __float2bfloat16(v);
        } else {
          const int t = r >> 1, bb = r & 1;
          if (c < 1024) {
            const int h = c >> 6, d = c & 63;
            const size_t o = (((size_t)(bb * NH + h)) * TSEQ + t) * DHD + d;
            o_qw[o] = __float2bfloat16(v + rwb[c]);
            o_qr[o] = __float2bfloat16(v + rrb[c]);
          } else if (c < 2048) {
            const int e = c - 1024, h = e >> 6, d = e & 63;
            o_k[(((size_t)(bb * NH + h)) * TSEQ + t) * DHD + d] = __float2bfloat16(v);
          } else {
            const int e = c - 2048, h = e >> 6, d = e & 63;
            o_vT[(((size_t)(bb * NH + h)) * DHD + d) * TSEQ + t] = __float2bfloat16(v);
          }
        }
      }
    }
  }
}

// ---------- fused causal rel-attention: LDS-staged, swapped core ----------
// Block = 4 waves = 64 q-rows; paired qblocks (p4, 31-p4) -> every block
// exactly 33 k-tile iters; 512 blocks = 2/CU, uniform, no merge.
// Per k-tile the BLOCK stages K(8KB)+V(8KB)+R-band(16KB) once via
// global_load_lds (linear dest + inverse-swizzled per-lane SOURCE; reads use
// the same XOR -> conflict-free, rule-21 both-sides pattern).
// K/V double-buffered (stage t+1 overlaps compute t; counted vmcnt(4) lets
// the KV prefetch stay in flight while R drains). R single-buffered, its
// latency hidden under S^T. Raw s_barrier (no implicit vmcnt(0) drain).
// Per-wave math = proven R5-R7 swapped core (16 rows/wave, in-register
// softmax, braw band shuffle, PV transposed, per-lane alpha/1l).
__global__ __launch_bounds__(256, 2) void k_attn(
    const __hip_bfloat16* __restrict__ qw, const __hip_bfloat16* __restrict__ qr,
    const __hip_bfloat16* __restrict__ kb, const __hip_bfloat16* __restrict__ vT,
    const __hip_bfloat16* __restrict__ rT, __hip_bfloat16* __restrict__ av) {
  const int tid = threadIdx.x, lane = tid & 63;
  const int w = __builtin_amdgcn_readfirstlane(tid >> 6);
  const int fr = lane & 15, fq = lane >> 4;
  const int l8 = lane >> 3, lb = lane & 7;
  const int bid = blockIdx.x;
  const int xcd = bid & 7, idx = bid >> 3;     // idx 0..63
  const int bh = xcd * 4 + (idx & 3);          // 4 heads per XCD
  const int pr = idx >> 2;                     // pair 0..15
  const int bb = bh >> 4, h = bh & 15;
  const char* Kp = (const char*)(kb + (size_t)bh * TSEQ * DHD);   // row t:128B
  const char* Vp = (const char*)(vT + (size_t)bh * DHD * TSEQ);   // row d:4096B
  const char* Rp = (const char*)(rT + (size_t)h * TSEQ * DHD);    // row t:128B

  __shared__ __align__(16) __hip_bfloat16 Ksm[2][64][64];   // 16 KB
  __shared__ __align__(16) __hip_bfloat16 Vsm[2][64][64];   // 16 KB
  __shared__ __align__(16) __hip_bfloat16 Rsm[128][64];     // 16 KB
  __shared__ __align__(16) float braw[4][16][88];           // 22.5 KB
  __shared__ __align__(16) __hip_bfloat16 plq[4][16][72];   // 9 KB

  // ---- per-lane constant offsets (zero loop VALU) ----
  const int swz = (lb << 4) ^ (l8 << 4);                 // staging src byte
  const int koff0 = (fq << 4) ^ ((fr & 7) << 4);         // swizzled read c=0
  const int koff1 = ((fq << 4) + 64) ^ ((fr & 7) << 4);  // swizzled read c=1
  const int rowA = w * 16 + l8;                          // KV stage rows
  const int kOff0 = rowA * 128 + swz, kOff1 = (rowA + 8) * 128 + swz;
  const int vOff0 = rowA * 4096 + swz, vOff1 = (rowA + 8) * 4096 + swz;
  // staging dests (linear, lane*16)
  char* kDstB = (char*)Ksm + w * 2048 + lane * 16;   // + buf*8192 (+1024 for s=1)
  char* vDstB = (char*)Vsm + w * 2048 + lane * 16;
  char* rDstB = (char*)Rsm + w * 4096 + lane * 16;   // + s*1024
  const f32x4 zero = {0.f, 0.f, 0.f, 0.f};

#pragma unroll
  for (int part = 0; part < 2; ++part) {
    const int p4 = part ? 31 - pr : pr;
    const int nk = p4 + 1;
    const int iw0 = p4 * 64 + w * 16;
    const __hip_bfloat16* qwp = qw + ((size_t)bh * TSEQ + iw0 + fr) * DHD + fq * 8;
    const __hip_bfloat16* qrp = qr + ((size_t)bh * TSEQ + iw0 + fr) * DHD + fq * 8;
    const bf16x8 qwf0 = ld_bf16x8(qwp), qwf1 = ld_bf16x8(qwp + 32);
    const bf16x8 qrf0 = ld_bf16x8(qrp), qrf1 = ld_bf16x8(qrp + 32);
    f32x4 o[4] = {};
    float mrow = -INFINITY, lrow = 0.f;

    // prologue: stage KV(0) -> buf0
    GLL16(Kp + kOff0, kDstB);
    GLL16(Kp + kOff1, kDstB + 1024);
    GLL16(Vp + vOff0, vDstB);
    GLL16(Vp + vOff1, vDstB + 1024);
    asm volatile("s_waitcnt vmcnt(0)" ::: "memory");
    __builtin_amdgcn_s_barrier();

    int rbase = 1984 - 64 * p4;
    int thr = iw0 + fr;
    const char* kTile = Kp + 8192;   // source base for tile kt+1
    const char* vTile = Vp + 128;
    for (int kt = 0; kt < nk; ++kt) {
      const int cur = kt & 1;
      const int curOff = cur << 13, nxtOff = (cur ^ 1) << 13;
      // ---- stage R(kt): 4 GLL (rows w*32+s*8+l8, clamp high) ----
#pragma unroll
      for (int s = 0; s < 4; ++s) {
        int g = rbase + w * 32 + s * 8 + l8;
        g = g > 2047 ? 2047 : g;
        GLL16(Rp + g * 128 + swz, rDstB + s * 1024);
      }
      // ---- stage KV(kt+1) -> other buf (always; pad-safe OOB on last) ----
      GLL16(kTile + kOff0, kDstB + nxtOff);
      GLL16(kTile + kOff1, kDstB + nxtOff + 1024);
      GLL16(vTile + vOff0, vDstB + nxtOff);
      GLL16(vTile + vOff1, vDstB + nxtOff + 1024);
      // ---- S^T from Ksm[cur] (staged prev iter) ----
      const char* kls = (const char*)Ksm + curOff + fr * 128;
      f32x4 st[4];
#pragma unroll
      for (int n = 0; n < 4; ++n) {
        st[n] = __builtin_amdgcn_mfma_f32_16x16x32_bf16(ld_bf16x8(kls + n * 2048 + koff0), qwf0, zero, 0, 0, 0);
        st[n] = __builtin_amdgcn_mfma_f32_16x16x32_bf16(ld_bf16x8(kls + n * 2048 + koff1), qwf1, st[n], 0, 0, 0);
      }
      // ---- wait R staged (KV prefetch stays in flight), all waves ----
      asm volatile("s_waitcnt vmcnt(4)" ::: "memory");
      __builtin_amdgcn_s_barrier();
      // ---- band from Rsm: D[m][q=fr] -> b128 braw write ----
      const char* rls = (const char*)Rsm + (48 - 16 * w + fr) * 128;
#pragma unroll
      for (int pp = 0; pp < 5; ++pp) {
        f32x4 br = __builtin_amdgcn_mfma_f32_16x16x32_bf16(ld_bf16x8(rls + pp * 2048 + koff0), qrf0, zero, 0, 0, 0);
        br = __builtin_amdgcn_mfma_f32_16x16x32_bf16(ld_bf16x8(rls + pp * 2048 + koff1), qrf1, br, 0, 0, 0);
        *reinterpret_cast<f32x4*>(&braw[w][fr][pp * 16 + 4 * fq]) = br;
      }
      // ---- scores + in-register online softmax (q = fr) ----
      const float* brd = &braw[w][fr][15 - fr];
      float mx = -INFINITY;
#pragma unroll
      for (int n = 0; n < 4; ++n) {
#pragma unroll
        for (int j = 0; j < 4; ++j) {
          const int koff = 16 * n + 4 * fq + j;
          const float s = (koff > thr) ? -INFINITY : (st[n][j] + brd[koff]) * 0.125f;
          st[n][j] = s;
          mx = fmaxf(mx, s);
        }
      }
      mx = fmaxf(mx, __shfl_xor(mx, 16));
      mx = fmaxf(mx, __shfl_xor(mx, 32));
      const float mn = fmaxf(mrow, mx);
      const float al = __expf(mrow - mn);
      mrow = mn;
      float rs = 0.f;
#pragma unroll
      for (int n = 0; n < 4; ++n)
#pragma unroll
        for (int j = 0; j < 4; ++j) {
          const float pv = __expf(st[n][j] - mn);
          st[n][j] = pv;
          rs += pv;
        }
      rs += __shfl_xor(rs, 16);
      rs += __shfl_xor(rs, 32);
      lrow = lrow * al + rs;
#pragma unroll
      for (int nd = 0; nd < 4; ++nd) o[nd] *= al;
      // ---- P store: packed b64 ----
      struct B4 { __hip_bfloat16 a, b, c, d; };
#pragma unroll
      for (int n = 0; n < 4; ++n) {
        B4 pk;
        pk.a = __float2bfloat16(st[n][0]);
        pk.b = __float2bfloat16(st[n][1]);
        pk.c = __float2bfloat16(st[n][2]);
        pk.d = __float2bfloat16(st[n][3]);
        *reinterpret_cast<B4*>(&plq[w][fr][16 * n + 4 * fq]) = pk;
      }
      // ---- O^T += V^T . P^T from Vsm[cur] ----
      const char* vls = (const char*)Vsm + curOff + fr * 128;
#pragma unroll
      for (int c = 0; c < 2; ++c) {
        const bf16x8 pf = ld_bf16x8(&plq[w][fr][8 * fq + 32 * c]);
#pragma unroll
        for (int nd = 0; nd < 4; ++nd)
          o[nd] = __builtin_amdgcn_mfma_f32_16x16x32_bf16(
              ld_bf16x8(vls + nd * 2048 + (c ? koff1 : koff0)), pf, o[nd], 0, 0, 0);
      }
      // ---- drain KV(kt+1), close the tile ----
      asm volatile("s_waitcnt vmcnt(0)" ::: "memory");
      __builtin_amdgcn_s_barrier();
      rbase += 64;
      thr -= 64;
      kTile += 8192;
      vTile += 128;
    }
    // ---- epilogue: per-lane 1/l, packed 8B stores; row i = iw0+fr ----
    const float linv = 1.f / lrow;
    const int i = iw0 + fr;
    struct B4 { __hip_bfloat16 a, b, c, d; };
#pragma unroll
    for (int nd = 0; nd < 4; ++nd) {
      B4 pack;
      pack.a = __float2bfloat16(o[nd][0] * linv);
      pack.b = __float2bfloat16(o[nd][1] * linv);
      pack.c = __float2bfloat16(o[nd][2] * linv);
      pack.d = __float2bfloat16(o[nd][3] * linv);
      *reinterpret_cast<B4*>(av + ((size_t)i * NB + bb) * DM + h * DHD + 16 * nd + 4 * fq) = pack;
    }
  }
}

extern "C" void kernel_launch(void* const* d_in, const int* in_sizes, int n_in,
                              void* d_out, int out_size, void* d_ws, size_t ws_size,
                              hipStream_t stream) {
  (void)in_sizes; (void)n_in; (void)out_size; (void)ws_size;
  const float* x    = (const float*)d_in[0];
  const float* pos  = (const float*)d_in[1];
  const float* ln_g = (const float*)d_in[2];
  const float* ln_b = (const float*)d_in[3];
  const float* Wqkv = (const float*)d_in[4];
  const float* Wr   = (const float*)d_in[5];
  const float* Wo   = (const float*)d_in[6];
  const float* rwb  = (const float*)d_in[7];
  const float* rrb  = (const float*)d_in[8];
  float* out = (float*)d_out;

  char* ws = (char*)d_ws;
  size_t off = 0;
  auto alloc = [&](size_t n) {
    char* p = ws + off; off += (n + 255) & ~(size_t)255; return p;
  };
  __hip_bfloat16* wqkvT = (__hip_bfloat16*)alloc((size_t)3072 * 1024 * 2);
  __hip_bfloat16* wrT   = (__hip_bfloat16*)alloc((size_t)1024 * 1024 * 2);
  __hip_bfloat16* woT   = (__hip_bfloat16*)alloc((size_t)1024 * 1024 * 2);
  __hip_bfloat16* posb  = (__hip_bfloat16*)alloc((size_t)2048 * 1024 * 2);
  __hip_bfloat16* xn    = (__hip_bfloat16*)alloc((size_t)4096 * 1024 * 2);
  __hip_bfloat16* qwb   = (__hip_bfloat16*)alloc((size_t)NB * NH * TSEQ * DHD * 2);
  __hip_bfloat16* qrb   = (__hip_bfloat16*)alloc((size_t)NB * NH * TSEQ * DHD * 2);
  __hip_bfloat16* kbb   = (__hip_bfloat16*)alloc((size_t)NB * NH * TSEQ * DHD * 2);
  __hip_bfloat16* vTb   = (__hip_bfloat16*)alloc((size_t)NB * NH * TSEQ * DHD * 2);
  __hip_bfloat16* rTb   = (__hip_bfloat16*)alloc((size_t)NH * TSEQ * DHD * 2);
  __hip_bfloat16* avb   = (__hip_bfloat16*)alloc((size_t)4096 * 1024 * 2);
  (void)alloc(64 * 1024);  // guard: over-stage of last k-tile reads past buffers

  const dim3 tb(32, 8);
  k_transpose_cast<<<dim3(3072 / 32, 1024 / 32), tb, 0, stream>>>(Wqkv, wqkvT, 1024, 3072);
  k_transpose_cast<<<dim3(1024 / 32, 1024 / 32), tb, 0, stream>>>(Wr, wrT, 1024, 1024);
  k_transpose_cast<<<dim3(1024 / 32, 1024 / 32), tb, 0, stream>>>(Wo, woT, 1024, 1024);
  k_cast_bf16<<<(2048 * 1024) / 1024, 256, 0, stream>>>(pos, posb);
  k_layernorm<<<4096, 256, 0, stream>>>(x, ln_g, ln_b, xn);
  k_gemm_bt<0><<<32 * 24, 256, 0, stream>>>(xn, wqkvT, 4096, 3072, 1024,
      nullptr, qwb, qrb, kbb, vTb, rwb, rrb, nullptr);
  k_gemm_bt<1><<<16 * 8, 256, 0, stream>>>(posb, wrT, 2048, 1024, 1024,
      nullptr, nullptr, nullptr, nullptr, nullptr, nullptr, nullptr, rTb);
  k_attn<<<512, 256, 0, stream>>>(qwb, qrb, kbb, vTb, rTb, avb);
  k_gemm_bt<2><<<32 * 8, 256, 0, stream>>>(avb, woT, 4096, 1024, 1024,
      out, nullptr, nullptr, nullptr, nullptr, nullptr, nullptr, nullptr);
}